// Round 6
// baseline (216.356 us; speedup 1.0000x reference)
//
#include <hip/hip_runtime.h>

// RoIAlign / crop-and-resize, TF2 half-pixel-center bilinear, POOL=7.
// fm: (256,256,512) fp32 NHWC; proposals: (N,4) int32 [x,y,w,h]; out: (N,7,7,512) fp32.
//
// R5: spatial locality via y-sort + contiguous-XCD partition.
//   k1: rank-sort boxes by y (O(N^2) count in LDS, deterministic), perm -> ws.
//   k2: xcd = blockIdx%8 owns boxes perm[xcd*N/8 .. +N/8) (a contiguous y-band
//       of the sorted order). Overlapping boxes hit the same XCD's L2 -> fewer
//       duplicate L2-miss (EA) fills; concurrent misses cluster in few fm rows
//       -> better DRAM page locality. FETCH_SIZE is L2-miss bytes, and the EA
//       path (~3.4 TB/s achieved vs 6.7 linear) is the measured wall.

constexpr int FW  = 256;   // feature map width
constexpr int FC  = 512;   // channels
constexpr int FC4 = FC / 4;

typedef float vfloat4 __attribute__((ext_vector_type(4)));

__device__ __forceinline__ void axis_coords(int start, int size, int p,
                                            int& c0, int& c1, float& frac) {
    // s = (p+0.5)*size/7 - 0.5, clipped to [0, size-1]; size >= 1 guaranteed.
    float s = ((float)p + 0.5f) * ((float)size / 7.0f) - 0.5f;
    s = fminf(fmaxf(s, 0.0f), (float)(size - 1));
    int i0 = (int)s;                 // s >= 0, truncation == floor
    int i1 = min(i0 + 1, size - 1);
    frac = s - (float)i0;
    c0 = start + i0;
    c1 = start + i1;
}

// ---- k1: deterministic rank-sort of boxes by y (N <= 1024, one block) ----
__global__ void sort_boxes_kernel(const int* __restrict__ props,
                                  int* __restrict__ perm, int N) {
    __shared__ int ys[1024];
    const int t = threadIdx.x;
    if (t < N) ys[t] = props[4 * t + 1];      // y coordinate
    __syncthreads();
    if (t < N) {
        const int y = ys[t];
        int rank = 0;
        for (int j = 0; j < N; ++j) {
            const int yj = ys[j];
            rank += (yj < y) || (yj == y && j < t);
        }
        perm[rank] = t;                       // sorted position -> original box
    }
}

// ---- k2: row gather, y-sorted boxes partitioned contiguously per XCD ----
__global__ __launch_bounds__(128) void roi_align_sorted_kernel(
        const float* __restrict__ fm,
        const int*   __restrict__ props,
        const int*   __restrict__ perm,
        float*       __restrict__ out,
        int boxes_per_xcd) {                  // N/8
    const int B    = blockIdx.x;
    const int xcd  = B & 7;                   // consecutive blocks round-robin XCDs
    const int slot = B >> 3;                  // 0 .. N*7/8-1, in-order per XCD
    const int n    = perm[xcd * boxes_per_xcd + slot / 7];
    const int py   = slot % 7;

    const int4 box = ((const int4*)props)[n]; // x, y, w, h

    int y0, y1;
    float fy;
    axis_coords(box.y, box.w, py, y0, y1, fy);
    const float gy = 1.0f - fy;

    int   x0[7], x1[7];
    float fx[7];
#pragma unroll
    for (int px = 0; px < 7; ++px)
        axis_coords(box.x, box.z, px, x0[px], x1[px], fx[px]);

    const vfloat4* __restrict__ r0 = (const vfloat4*)(fm + (size_t)y0 * FW * FC);
    const vfloat4* __restrict__ r1 = (const vfloat4*)(fm + (size_t)y1 * FW * FC);
    vfloat4* __restrict__ po = (vfloat4*)(out + ((size_t)n * 49 + (size_t)py * 7) * FC);

    const int c = threadIdx.x;                // 0..127 -> float4 lane (FC4 = 128)

    // 28 independent loads in flight per wave.
    vfloat4 v00[7], v01[7], v10[7], v11[7];
#pragma unroll
    for (int px = 0; px < 7; ++px) {
        v00[px] = r0[x0[px] * FC4 + c];
        v01[px] = r0[x1[px] * FC4 + c];
        v10[px] = r1[x0[px] * FC4 + c];
        v11[px] = r1[x1[px] * FC4 + c];
    }

#pragma unroll
    for (int px = 0; px < 7; ++px) {
        const float fxp = fx[px], gxp = 1.0f - fx[px];
        vfloat4 top = v00[px] * gxp + v01[px] * fxp;
        vfloat4 bot = v10[px] * gxp + v11[px] * fxp;
        vfloat4 r   = top * gy + bot * fy;
        __builtin_nontemporal_store(r, &po[px * FC4 + c]);
    }
}

// Fallback (no sort/swizzle) for N not expressible in the partition scheme.
__global__ __launch_bounds__(128) void roi_align_row_kernel(
        const float* __restrict__ fm,
        const int*   __restrict__ props,
        float*       __restrict__ out) {
    const int blk = blockIdx.x;
    const int n   = blk / 7;
    const int py  = blk - n * 7;

    const int4 box = ((const int4*)props)[n];
    int y0, y1;
    float fy;
    axis_coords(box.y, box.w, py, y0, y1, fy);
    const float gy = 1.0f - fy;

    int   x0[7], x1[7];
    float fx[7];
#pragma unroll
    for (int px = 0; px < 7; ++px)
        axis_coords(box.x, box.z, px, x0[px], x1[px], fx[px]);

    const vfloat4* __restrict__ r0 = (const vfloat4*)(fm + (size_t)y0 * FW * FC);
    const vfloat4* __restrict__ r1 = (const vfloat4*)(fm + (size_t)y1 * FW * FC);
    vfloat4* __restrict__ po = (vfloat4*)(out + ((size_t)n * 49 + (size_t)py * 7) * FC);
    const int c = threadIdx.x;

    vfloat4 v00[7], v01[7], v10[7], v11[7];
#pragma unroll
    for (int px = 0; px < 7; ++px) {
        v00[px] = r0[x0[px] * FC4 + c];
        v01[px] = r0[x1[px] * FC4 + c];
        v10[px] = r1[x0[px] * FC4 + c];
        v11[px] = r1[x1[px] * FC4 + c];
    }
#pragma unroll
    for (int px = 0; px < 7; ++px) {
        const float fxp = fx[px], gxp = 1.0f - fx[px];
        vfloat4 top = v00[px] * gxp + v01[px] * fxp;
        vfloat4 bot = v10[px] * gxp + v11[px] * fxp;
        vfloat4 r   = top * gy + bot * fy;
        __builtin_nontemporal_store(r, &po[px * FC4 + c]);
    }
}

extern "C" void kernel_launch(void* const* d_in, const int* in_sizes, int n_in,
                              void* d_out, int out_size, void* d_ws, size_t ws_size,
                              hipStream_t stream) {
    const float* fm    = (const float*)d_in[0];
    const int*   props = (const int*)d_in[1];
    float*       out   = (float*)d_out;
    int*         perm  = (int*)d_ws;

    const int N = in_sizes[1] / 4;            // 512 proposals
    if (N % 8 == 0 && N <= 1024) {
        sort_boxes_kernel<<<1, N, 0, stream>>>(props, perm, N);
        roi_align_sorted_kernel<<<N * 7, 128, 0, stream>>>(fm, props, perm, out, N / 8);
    } else {
        roi_align_row_kernel<<<N * 7, 128, 0, stream>>>(fm, props, out);
    }
}

// Round 7
// 196.837 us; speedup vs baseline: 1.0992x; 1.0992x over previous
//
#include <hip/hip_runtime.h>

// RoIAlign / crop-and-resize, TF2 half-pixel-center bilinear, POOL=7.
// fm: (256,256,512) fp32 NHWC; proposals: (N,4) int32 [x,y,w,h]; out: (N,7,7,512) fp32.
//
// R6: forced 28-deep MLP. R3's profile showed VGPR_Count=36 -> the compiler
// had re-batched the "28 independent loads" into ~5-load groups (28 float4
// values need 112+ VGPRs). sched_barrier(0) between the load loop and the
// compute loop pins all 28 loads before any use; __launch_bounds__(128,1)
// lifts the VGPR cap so they stay in registers (no spill: ~160 < 512).
// Discriminates outstanding-bytes-limited (expect ~55 -> ~35-40 us) vs
// scatter-throughput-throttled (expect neutral -> declare floor).
// R5's y-sort reverted (-17 us serial sort kernel, no gather benefit).

constexpr int FW  = 256;   // feature map width
constexpr int FC  = 512;   // channels
constexpr int FC4 = FC / 4;

typedef float vfloat4 __attribute__((ext_vector_type(4)));

__device__ __forceinline__ void axis_coords(int start, int size, int p,
                                            int& c0, int& c1, float& frac) {
    // s = (p+0.5)*size/7 - 0.5, clipped to [0, size-1]; size >= 1 guaranteed.
    float s = ((float)p + 0.5f) * ((float)size / 7.0f) - 0.5f;
    s = fminf(fmaxf(s, 0.0f), (float)(size - 1));
    int i0 = (int)s;                 // s >= 0, truncation == floor
    int i1 = min(i0 + 1, size - 1);
    frac = s - (float)i0;
    c0 = start + i0;
    c1 = start + i1;
}

__global__ __launch_bounds__(128, 1) void roi_align_mlp_kernel(
        const float* __restrict__ fm,
        const int*   __restrict__ props,
        float*       __restrict__ out) {
    const int blk = blockIdx.x;               // n*7 + py
    const int n   = blk / 7;
    const int py  = blk - n * 7;

    const int4 box = ((const int4*)props)[n]; // x, y, w, h

    int y0, y1;
    float fy;
    axis_coords(box.y, box.w, py, y0, y1, fy);
    const float gy = 1.0f - fy;

    int   x0[7], x1[7];
    float fx[7];
#pragma unroll
    for (int px = 0; px < 7; ++px)
        axis_coords(box.x, box.z, px, x0[px], x1[px], fx[px]);

    const vfloat4* __restrict__ r0 = (const vfloat4*)(fm + (size_t)y0 * FW * FC);
    const vfloat4* __restrict__ r1 = (const vfloat4*)(fm + (size_t)y1 * FW * FC);
    vfloat4* __restrict__ po = (vfloat4*)(out + ((size_t)n * 49 + (size_t)py * 7) * FC);

    const int c = threadIdx.x;                // 0..127 -> float4 lane (FC4 = 128)

    // All 28 loads issued before ANY use — sched_barrier(0) pins the order,
    // forcing the register allocator to keep all 28 float4s live (~112 VGPR).
    vfloat4 v00[7], v01[7], v10[7], v11[7];
#pragma unroll
    for (int px = 0; px < 7; ++px) {
        v00[px] = r0[x0[px] * FC4 + c];
        v01[px] = r0[x1[px] * FC4 + c];
        v10[px] = r1[x0[px] * FC4 + c];
        v11[px] = r1[x1[px] * FC4 + c];
    }
    __builtin_amdgcn_sched_barrier(0);        // nothing crosses this line

#pragma unroll
    for (int px = 0; px < 7; ++px) {
        const float fxp = fx[px], gxp = 1.0f - fx[px];
        vfloat4 top = v00[px] * gxp + v01[px] * fxp;
        vfloat4 bot = v10[px] * gxp + v11[px] * fxp;
        vfloat4 r   = top * gy + bot * fy;
        __builtin_nontemporal_store(r, &po[px * FC4 + c]);
    }
}

extern "C" void kernel_launch(void* const* d_in, const int* in_sizes, int n_in,
                              void* d_out, int out_size, void* d_ws, size_t ws_size,
                              hipStream_t stream) {
    const float* fm    = (const float*)d_in[0];
    const int*   props = (const int*)d_in[1];
    float*       out   = (float*)d_out;

    const int N = in_sizes[1] / 4;            // 512 proposals
    roi_align_mlp_kernel<<<N * 7, 128, 0, stream>>>(fm, props, out);
}